// Round 11
// baseline (457.242 us; speedup 1.0000x reference)
//
#include <hip/hip_runtime.h>
#include <hip/hip_bf16.h>

typedef __bf16 bf16_t;
typedef __bf16 bf16x8 __attribute__((ext_vector_type(8)));
typedef __bf16 bf16x4 __attribute__((ext_vector_type(4)));
typedef float  floatx4 __attribute__((ext_vector_type(4)));

static __device__ __forceinline__ floatx4 mfma16(bf16x8 a, bf16x8 b, floatx4 c) {
  return __builtin_amdgcn_mfma_f32_16x16x32_bf16(a, b, c, 0, 0, 0);
}

// async global->LDS, 16B per lane; LDS dest = wave-uniform base + lane*16.
typedef __attribute__((address_space(3))) void lds_vp;
typedef __attribute__((address_space(1))) void glb_vp;
#define GLDS16(g, l) \
  __builtin_amdgcn_global_load_lds((glb_vp*)(g), (lds_vp*)(l), 16, 0, 0)

// ---------------- fused fp32 -> bf16 convert (x, W_QKV, W_O) ----------------
__global__ void cvt_all_kernel(const float* __restrict__ x,
                               const float* __restrict__ wqkv,
                               const float* __restrict__ wo,
                               bf16_t* __restrict__ xb,
                               bf16_t* __restrict__ wqkvb,
                               bf16_t* __restrict__ wob) {
  int i = blockIdx.x * blockDim.x + threadIdx.x;     // 0..1310719 float4s
  const float4* src; bf16x4* dst; int off;
  if (i < 1048576)      { src = (const float4*)x;    dst = (bf16x4*)xb;    off = i; }
  else if (i < 1245184) { src = (const float4*)wqkv; dst = (bf16x4*)wqkvb; off = i - 1048576; }
  else                  { src = (const float4*)wo;   dst = (bf16x4*)wob;   off = i - 1245184; }
  float4 v = src[off];
  bf16x4 o;
  o[0] = (bf16_t)v.x; o[1] = (bf16_t)v.y; o[2] = (bf16_t)v.z; o[3] = (bf16_t)v.w;
  dst[off] = o;
}

// ---------------- QKV GEMM: C(M,N) = A(M,K) * B(N,K)^T ----------------
// Epilogues write attn-ready layouts:
//   Q  [bh][t][64] pre-scaled by 0.125*log2e (softmax in log2 domain)
//   Kf [bh][t>>4][d>>5][lane][8]  MFMA-A-fragment-linear: lane=((d&31)>>3)*16+(t&15)
//   Vf [bh][t'>>5][d>>4][lane][8] V^T fragment-linear:    lane=((t'>>3)&3)*16+(d&15)
// so attn reads every fragment as ONE coalesced global_load_dwordx4 (no LDS).
__global__ __launch_bounds__(256) void gemm_qkv(
    const bf16_t* __restrict__ A, const bf16_t* __restrict__ B,
    bf16_t* __restrict__ Qo, bf16_t* __restrict__ Ko, bf16_t* __restrict__ Vto)
{
  __shared__ __align__(16) bf16_t As[2][128 * 64];
  __shared__ __align__(16) bf16_t Bs[2][128 * 64];
  const int tid  = threadIdx.x;
  const int lane = tid & 63;
  const int w    = tid >> 6;
  const int quad = lane >> 4;
  const int l15  = lane & 15;
  const int l7   = lane & 7;
  const int wm   = w & 1;
  const int wn   = w >> 1;
  const int K    = 512;

  floatx4 acc[4][4];
  #pragma unroll
  for (int i = 0; i < 4; ++i)
    #pragma unroll
    for (int j = 0; j < 4; ++j)
      acc[i][j] = (floatx4){0.f, 0.f, 0.f, 0.f};

  const bf16_t* Ab = A + (size_t)blockIdx.x * 128 * K;
  const bf16_t* Bb = B + (size_t)blockIdx.y * 128 * K;

  auto stage = [&](int buf, int k0) {
    #pragma unroll
    for (int i = 0; i < 4; ++i) {
      int c = tid + 256 * i;
      int row = c >> 3, colc = c & 7;
      int gofs = ((colc ^ (row & 7)) << 3);
      GLDS16(&Ab[(size_t)row * K + k0 + gofs], &As[buf][c * 8]);
      GLDS16(&Bb[(size_t)row * K + k0 + gofs], &Bs[buf][c * 8]);
    }
  };

  stage(0, 0);
  for (int it = 0; it < 8; ++it) {
    const int cur = it & 1;
    __syncthreads();
    if (it + 1 < 8) stage(cur ^ 1, (it + 1) << 6);
    #pragma unroll
    for (int ks = 0; ks < 2; ++ks) {
      bf16x8 af[4], bfr[4];
      #pragma unroll
      for (int t = 0; t < 4; ++t) {
        af[t]  = *(const bf16x8*)&As[cur][(wm * 64 + t * 16 + l15) * 64 +
                                         (((ks * 4 + quad) ^ l7) << 3)];
        bfr[t] = *(const bf16x8*)&Bs[cur][(wn * 64 + t * 16 + l15) * 64 +
                                         (((ks * 4 + quad) ^ l7) << 3)];
      }
      #pragma unroll
      for (int mt = 0; mt < 4; ++mt)
        #pragma unroll
        for (int nt = 0; nt < 4; ++nt)
          acc[mt][nt] = mfma16(af[mt], bfr[nt], acc[mt][nt]);
    }
  }

  if (blockIdx.y < 8) {
    // ---- Q / K scatter epilogue ----
    #pragma unroll
    for (int mt = 0; mt < 4; ++mt) {
      #pragma unroll
      for (int nt = 0; nt < 4; ++nt) {
        #pragma unroll
        for (int r = 0; r < 4; ++r) {
          int m = blockIdx.x * 128 + wm * 64 + mt * 16 + quad * 4 + r;
          int n = blockIdx.y * 128 + wn * 64 + nt * 16 + l15;
          float v = acc[mt][nt][r];
          int b = m >> 12, t = m & 4095;
          int h = (n >> 6) & 7, d = n & 63;
          size_t bh = (size_t)(b * 8 + h);
          if (n < 512)   // fold 1/sqrt(64) * log2(e) -> softmax in log2 domain
            Qo[bh * 262144 + (size_t)t * 64 + d] = (bf16_t)(v * 0.18033688f);
          else           // K fragment-linear
            Ko[bh * 262144 +
               (size_t)((((t >> 4) * 2 + (d >> 5)) * 512) +
                        ((((d & 31) >> 3) * 16 + (t & 15)) * 8) + (d & 7))] =
                (bf16_t)v;
        }
      }
    }
  } else {
    // ---- V epilogue: transpose through LDS (As region, 32 KB) ----
    __syncthreads();                       // everyone done reading As/Bs
    bf16_t* L = &As[0][0];                 // [n_local][m swizzled] 128x128
    #pragma unroll
    for (int mt = 0; mt < 4; ++mt)
      #pragma unroll
      for (int nt = 0; nt < 4; ++nt) {
        int n_l = wn * 64 + nt * 16 + l15;
        int mc  = wm * 8 + mt * 2 + (quad >> 1);     // m-chunk of 8
        bf16x4 v4;
        #pragma unroll
        for (int r = 0; r < 4; ++r) v4[r] = (bf16_t)acc[mt][nt][r];
        *(bf16x4*)&L[n_l * 128 + ((mc ^ (n_l & 15)) << 3) + (quad & 1) * 4] = v4;
      }
    __syncthreads();
    const int t0 = (blockIdx.x & 31) * 128;
    const int b  = blockIdx.x >> 5;
    #pragma unroll
    for (int i = 0; i < 8; ++i) {
      int c = tid + 256 * i;               // 0..2047: n_l = c>>4, tc = c&15
      int n_l = c >> 4, tc = c & 15;
      int h = ((blockIdx.y - 8) << 1) | (n_l >> 6);
      int d = n_l & 63;
      size_t bh = (size_t)(b * 8 + h);
      int base0 = (tc >> 2) * 32 + (tc & 3) * 4;
      bf16x4 lo = *(const bf16x4*)&L[n_l * 128 +
                     (((base0 >> 3) ^ (n_l & 15)) << 3) + (base0 & 7)];
      bf16x4 hi = *(const bf16x4*)&L[n_l * 128 +
                     ((((base0 + 16) >> 3) ^ (n_l & 15)) << 3) + (base0 & 7)];
      bf16x8 o;
      #pragma unroll
      for (int e = 0; e < 4; ++e) { o[e] = lo[e]; o[e + 4] = hi[e]; }
      int T = t0 + tc * 8;                 // t' base of this 8-chunk
      *(bf16x8*)&Vto[bh * 262144 +
                     (size_t)((((T >> 5) * 4 + (d >> 4)) * 512) +
                              ((((T >> 3) & 3) * 16 + (d & 15)) * 8))] = o;
    }
  }
}

// ---------------- output GEMM: out(8192,512) = Ob(8192,512) * Wo(512,512)^T ----
__global__ __launch_bounds__(256) void gemm_out(
    const bf16_t* __restrict__ A, const bf16_t* __restrict__ B,
    float* __restrict__ Cf)
{
  __shared__ __align__(16) bf16_t As[2][64 * 64];
  __shared__ __align__(16) bf16_t Bs[2][128 * 64];
  const int tid  = threadIdx.x;
  const int lane = tid & 63;
  const int w    = tid >> 6;               // 0..3, owns n-range w*32..+32
  const int quad = lane >> 4;
  const int l15  = lane & 15;
  const int l7   = lane & 7;

  floatx4 acc[4][2];
  #pragma unroll
  for (int i = 0; i < 4; ++i)
    #pragma unroll
    for (int j = 0; j < 2; ++j)
      acc[i][j] = (floatx4){0.f, 0.f, 0.f, 0.f};

  const bf16_t* Ab = A + (size_t)blockIdx.x * 64 * 512;
  const bf16_t* Bb = B + (size_t)blockIdx.y * 128 * 512;

  auto stage = [&](int buf, int k0) {
    #pragma unroll
    for (int i = 0; i < 2; ++i) {          // A: 512 chunks
      int c = tid + 256 * i;
      int row = c >> 3, colc = c & 7;
      GLDS16(&Ab[(size_t)row * 512 + k0 + ((colc ^ (row & 7)) << 3)],
             &As[buf][c * 8]);
    }
    #pragma unroll
    for (int i = 0; i < 4; ++i) {          // B: 1024 chunks
      int c = tid + 256 * i;
      int row = c >> 3, colc = c & 7;
      GLDS16(&Bb[(size_t)row * 512 + k0 + ((colc ^ (row & 7)) << 3)],
             &Bs[buf][c * 8]);
    }
  };

  stage(0, 0);
  for (int it = 0; it < 8; ++it) {
    const int cur = it & 1;
    __syncthreads();
    if (it + 1 < 8) stage(cur ^ 1, (it + 1) << 6);
    #pragma unroll
    for (int ks = 0; ks < 2; ++ks) {
      bf16x8 af[4], bfr[2];
      #pragma unroll
      for (int t = 0; t < 4; ++t)
        af[t]  = *(const bf16x8*)&As[cur][(t * 16 + l15) * 64 +
                                         (((ks * 4 + quad) ^ l7) << 3)];
      #pragma unroll
      for (int t = 0; t < 2; ++t)
        bfr[t] = *(const bf16x8*)&Bs[cur][(w * 32 + t * 16 + l15) * 64 +
                                         (((ks * 4 + quad) ^ l7) << 3)];
      #pragma unroll
      for (int mt = 0; mt < 4; ++mt)
        #pragma unroll
        for (int nt = 0; nt < 2; ++nt)
          acc[mt][nt] = mfma16(af[mt], bfr[nt], acc[mt][nt]);
    }
  }

  #pragma unroll
  for (int mt = 0; mt < 4; ++mt)
    #pragma unroll
    for (int nt = 0; nt < 2; ++nt)
      #pragma unroll
      for (int r = 0; r < 4; ++r) {
        int m = blockIdx.x * 64 + mt * 16 + quad * 4 + r;
        int n = blockIdx.y * 128 + w * 32 + nt * 16 + l15;
        Cf[(size_t)m * 512 + n] = acc[mt][nt][r];
      }
}

// ---- causal flash attention: register-direct, 2 blocks/CU, 4 waves/SIMD ----
// 512 blocks x 512 threads, LDS 66 KB -> 2 blocks/CU = 16 waves/CU = 4/SIMD
// (R10 had 1 block/CU = 2/SIMD: MFMA 33% + VALU 32% + L2 ~34% serialized within
// waves; 4 independent streams per SIMD overlap them). Block owns the 64-row
// q-block pair (q64A=63-y, q64B=y) of one bh, processed SEQUENTIALLY; 8 waves
// = k64 residues mod 8 -> per-wave units = 8.1 +- 1, uniform across waves AND
// blocks. Inner body identical to R10 (64q x 64k: 72 MFMA / 16 coalesced
// dwordx4 fragment loads / 64 exp2; zero main-loop barriers). Epilogue per
// tile: two d-half rounds over PART[kq][64q][32d] f32 (64 KB, XOR chunk
// swizzle, bank-even) + all-thread 8-way merge + normalize + direct Og store.
// No-max log2-domain softmax (scores bounded, fp32-safe).
__global__ __launch_bounds__(512, 4) void attn_kernel(
    const bf16_t* __restrict__ Qg, const bf16_t* __restrict__ Kf,
    const bf16_t* __restrict__ Vf, bf16_t* __restrict__ Og)
{
  // PART[kq 0..7][64q][32d] f32 = 65536 B ; PL[kq][64q] f32 = 2048 B
  __shared__ __align__(16) bf16_t smem[33792];   // 67,584 B

  const int tid  = threadIdx.x;
  const int lane = tid & 63;
  const int kq   = tid >> 6;               // wave = k64 residue class 0..7
  const int quad = lane >> 4;
  const int l15  = lane & 15;

  const int id = blockIdx.x;               // 0..511
  const int bh = 2 * (id & 7) + ((id >> 3) & 1);   // 2 bh per XCD (L2 reuse)
  const int y  = id >> 4;                  // 0..31
  const int q64A = 63 - y, q64B = y;
  const size_t bh_off = (size_t)bh * 262144;
  const int b = bh >> 3, h = bh & 7;

  const bf16_t* Kb_ = Kf + bh_off;
  const bf16_t* Vb_ = Vf + bh_off;
  const floatx4 z4 = (floatx4){0.f, 0.f, 0.f, 0.f};
  bf16x8 ones;
  #pragma unroll
  for (int i = 0; i < 8; ++i) ones[i] = (bf16_t)1.0f;

  for (int ph = 0; ph < 2; ++ph) {
    const int q64 = ph ? q64B : q64A;      // wave's 64-row q-block index
    const int qbase = q64 * 64;

    // Q fragments (pre-scaled by 0.125*log2e): 4 q-blocks of 16 rows
    bf16x8 aq0[4], aq1[4];
    #pragma unroll
    for (int qb = 0; qb < 4; ++qb) {
      const bf16_t* Qp = Qg + bh_off + (size_t)(qbase + qb * 16 + l15) * 64;
      aq0[qb] = *(const bf16x8*)&Qp[quad * 8];
      aq1[qb] = *(const bf16x8*)&Qp[32 + quad * 8];
    }

    floatx4 acc_o[4][4], acc_l[4];
    #pragma unroll
    for (int qb = 0; qb < 4; ++qb) {
      #pragma unroll
      for (int dt = 0; dt < 4; ++dt) acc_o[qb][dt] = (floatx4){0.f, 0.f, 0.f, 0.f};
      acc_l[qb] = (floatx4){0.f, 0.f, 0.f, 0.f};
    }

    for (int k64 = kq; k64 <= q64; k64 += 8) {
      const bf16_t* Kp = Kb_ + (size_t)k64 * 4096;   // 8 K-frags of 512 elems
      const bf16_t* Vp = Vb_ + (size_t)k64 * 4096;   // 8 V-frags of 512 elems
      // ---- K fragment loads: coalesced, L2-hot ----
      bf16x8 bk0[4], bk1[4];
      #pragma unroll
      for (int nt = 0; nt < 4; ++nt) {
        bk0[nt] = *(const bf16x8*)&Kp[(nt * 2 + 0) * 512 + lane * 8];
        bk1[nt] = *(const bf16x8*)&Kp[(nt * 2 + 1) * 512 + lane * 8];
      }
      // ---- S^T = K Q^T : 64 k-rows x 64 q-cols ----
      floatx4 s[4][4];                     // [qb][nt]
      #pragma unroll
      for (int nt = 0; nt < 4; ++nt) {
        s[0][nt] = mfma16(bk0[nt], aq0[0], z4);
        s[1][nt] = mfma16(bk0[nt], aq0[1], z4);
        s[2][nt] = mfma16(bk0[nt], aq0[2], z4);
        s[3][nt] = mfma16(bk0[nt], aq0[3], z4);
      }
      #pragma unroll
      for (int nt = 0; nt < 4; ++nt)
        #pragma unroll
        for (int qb = 0; qb < 4; ++qb)
          s[qb][nt] = mfma16(bk1[nt], aq1[qb], s[qb][nt]);
      // ---- V fragment loads (latency hides under exp2) ----
      bf16x8 av[2][4];
      #pragma unroll
      for (int kc = 0; kc < 2; ++kc)
        #pragma unroll
        for (int dt = 0; dt < 4; ++dt)
          av[kc][dt] = *(const bf16x8*)&Vp[(kc * 4 + dt) * 512 + lane * 8];
      // ---- no-max softmax, log2 domain ----
      if (k64 == q64) {                    // diagonal 64-block: mask k > q
        #pragma unroll
        for (int qb = 0; qb < 4; ++qb)
          #pragma unroll
          for (int nt = 0; nt < 4; ++nt)
            #pragma unroll
            for (int r = 0; r < 4; ++r)
              if (nt * 16 + quad * 4 + r > qb * 16 + l15)
                s[qb][nt][r] = -3.0e38f;
      }
      #pragma unroll
      for (int qb = 0; qb < 4; ++qb)
        #pragma unroll
        for (int nt = 0; nt < 4; ++nt)
          #pragma unroll
          for (int r = 0; r < 4; ++r)
            s[qb][nt][r] = __builtin_amdgcn_exp2f(s[qb][nt][r]);
      // ---- PV: O^T += V^T P^T ; l += 1^T P^T ----
      #pragma unroll
      for (int kc = 0; kc < 2; ++kc) {
        bf16x8 pb[4];
        #pragma unroll
        for (int qb = 0; qb < 4; ++qb)
          #pragma unroll
          for (int r = 0; r < 4; ++r) {
            pb[qb][r]     = (bf16_t)s[qb][kc * 2][r];
            pb[qb][r + 4] = (bf16_t)s[qb][kc * 2 + 1][r];
          }
        #pragma unroll
        for (int qb = 0; qb < 4; ++qb)
          acc_l[qb] = mfma16(ones, pb[qb], acc_l[qb]);
        #pragma unroll
        for (int dt = 0; dt < 4; ++dt)
          #pragma unroll
          for (int qb = 0; qb < 4; ++qb)
            acc_o[qb][dt] = mfma16(av[kc][dt], pb[qb], acc_o[qb][dt]);
      }
    }

    // ---- epilogue: two d-half rounds, 8-way k-partial merge in LDS ----
    #pragma unroll
    for (int hd = 0; hd < 2; ++hd) {
      if (ph | hd) __syncthreads();        // prior merge reads done
      {                                    // write this wave's partial half
        float* Pw  = (float*)&smem[0] + kq * 2048;      // [64q][32d]
        float* PLw = (float*)&smem[32768];              // [kq][64q]
        #pragma unroll
        for (int qb = 0; qb < 4; ++qb) {
          int q = qb * 16 + l15;
          #pragma unroll
          for (int t = 0; t < 2; ++t) {    // logical chunk = t*4+quad (4d each)
            int cw = (t * 4 + quad) ^ (q & 7);          // bank-even XOR swizzle
            *(floatx4*)&Pw[q * 32 + cw * 4] = acc_o[qb][hd * 2 + t];
          }
          if (hd == 0 && quad == 0) PLw[kq * 64 + q] = acc_l[qb][0];
        }
      }
      __syncthreads();
      {                                    // all-thread merge + store
        int q = tid >> 3, c = tid & 7;     // 64 q x 8 chunks of 4d
        const float* PB = (const float*)&smem[0];
        const float* PL = (const float*)&smem[32768];
        floatx4 ssum = (floatx4){0.f, 0.f, 0.f, 0.f};
        float suml = 0.f;
        #pragma unroll
        for (int k = 0; k < 8; ++k) {
          const float* Pk = PB + k * 2048 + q * 32;
          floatx4 u = *(const floatx4*)&Pk[(c ^ (q & 7)) * 4];
          #pragma unroll
          for (int r = 0; r < 4; ++r) ssum[r] += u[r];
          suml += PL[k * 64 + q];
        }
        float rl = 1.0f / suml;
        bf16x4 o4;
        #pragma unroll
        for (int r = 0; r < 4; ++r) o4[r] = (bf16_t)(ssum[r] * rl);
        int row = qbase + q;
        *(bf16x4*)&Og[((size_t)b * 4096 + row) * 512 + h * 64 + hd * 32 + c * 4] = o4;
      }
    }
  }
}

// ---------------- launcher ----------------
extern "C" void kernel_launch(void* const* d_in, const int* in_sizes, int n_in,
                              void* d_out, int out_size, void* d_ws, size_t ws_size,
                              hipStream_t stream) {
  const float* x    = (const float*)d_in[0];   // (2,4096,512)
  const float* wqkv = (const float*)d_in[1];   // (1536,512)
  const float* wo   = (const float*)d_in[2];   // (512,512)
  float* out = (float*)d_out;                  // (2,4096,512) fp32

  char* ws = (char*)d_ws;
  bf16_t* xb    = (bf16_t*)(ws);                 //  8 MB (reused as Ob after gemm1)
  bf16_t* wqkvb = (bf16_t*)(ws + 8388608);       //  1.5 MB
  bf16_t* wob   = (bf16_t*)(ws + 9961472);       //  0.5 MB
  bf16_t* Qb    = (bf16_t*)(ws + 10485760);      //  8 MB  [bh][t][64], pre-scaled
  bf16_t* Kfb   = (bf16_t*)(ws + 18874368);      //  8 MB  K fragment-linear
  bf16_t* Vfb   = (bf16_t*)(ws + 27262976);      //  8 MB  V^T fragment-linear
  bf16_t* Ob    = xb;                            //  alias: gemm1 done with xb
  // total 35,651,584 bytes

  cvt_all_kernel<<<5120, 256, 0, stream>>>(x, wqkv, wo, xb, wqkvb, wob);

  gemm_qkv<<<dim3(64, 12), 256, 0, stream>>>(xb, wqkvb, Qb, Kfb, Vfb);
  attn_kernel<<<dim3(512), 512, 0, stream>>>(Qb, Kfb, Vfb, Ob);
  gemm_out<<<dim3(128, 4), 256, 0, stream>>>(Ob, wob, out);
}

// Round 12
// 152.782 us; speedup vs baseline: 2.9928x; 2.9928x over previous
//
#include <hip/hip_runtime.h>
#include <hip/hip_bf16.h>

typedef __bf16 bf16_t;
typedef __bf16 bf16x8 __attribute__((ext_vector_type(8)));
typedef __bf16 bf16x4 __attribute__((ext_vector_type(4)));
typedef float  floatx4 __attribute__((ext_vector_type(4)));

static __device__ __forceinline__ floatx4 mfma16(bf16x8 a, bf16x8 b, floatx4 c) {
  return __builtin_amdgcn_mfma_f32_16x16x32_bf16(a, b, c, 0, 0, 0);
}

// async global->LDS, 16B per lane; LDS dest = wave-uniform base + lane*16.
typedef __attribute__((address_space(3))) void lds_vp;
typedef __attribute__((address_space(1))) void glb_vp;
#define GLDS16(g, l) \
  __builtin_amdgcn_global_load_lds((glb_vp*)(g), (lds_vp*)(l), 16, 0, 0)

// ---------------- fused fp32 -> bf16 convert (x, W_QKV, W_O) ----------------
__global__ void cvt_all_kernel(const float* __restrict__ x,
                               const float* __restrict__ wqkv,
                               const float* __restrict__ wo,
                               bf16_t* __restrict__ xb,
                               bf16_t* __restrict__ wqkvb,
                               bf16_t* __restrict__ wob) {
  int i = blockIdx.x * blockDim.x + threadIdx.x;     // 0..1310719 float4s
  const float4* src; bf16x4* dst; int off;
  if (i < 1048576)      { src = (const float4*)x;    dst = (bf16x4*)xb;    off = i; }
  else if (i < 1245184) { src = (const float4*)wqkv; dst = (bf16x4*)wqkvb; off = i - 1048576; }
  else                  { src = (const float4*)wo;   dst = (bf16x4*)wob;   off = i - 1245184; }
  float4 v = src[off];
  bf16x4 o;
  o[0] = (bf16_t)v.x; o[1] = (bf16_t)v.y; o[2] = (bf16_t)v.z; o[3] = (bf16_t)v.w;
  dst[off] = o;
}

// ---------------- QKV GEMM: C(M,N) = A(M,K) * B(N,K)^T ----------------
// Epilogues write attn-ready layouts:
//   Q  [bh][t][64] pre-scaled by 0.125*log2e (softmax in log2 domain)
//   Kf [bh][t>>4][d>>5][lane][8]  MFMA-A-fragment-linear: lane=((d&31)>>3)*16+(t&15)
//   Vf [bh][t'>>5][d>>4][lane][8] V^T fragment-linear:    lane=((t'>>3)&3)*16+(d&15)
// so attn reads every fragment as ONE coalesced global_load_dwordx4 (no LDS).
__global__ __launch_bounds__(256) void gemm_qkv(
    const bf16_t* __restrict__ A, const bf16_t* __restrict__ B,
    bf16_t* __restrict__ Qo, bf16_t* __restrict__ Ko, bf16_t* __restrict__ Vto)
{
  __shared__ __align__(16) bf16_t As[2][128 * 64];
  __shared__ __align__(16) bf16_t Bs[2][128 * 64];
  const int tid  = threadIdx.x;
  const int lane = tid & 63;
  const int w    = tid >> 6;
  const int quad = lane >> 4;
  const int l15  = lane & 15;
  const int l7   = lane & 7;
  const int wm   = w & 1;
  const int wn   = w >> 1;
  const int K    = 512;

  floatx4 acc[4][4];
  #pragma unroll
  for (int i = 0; i < 4; ++i)
    #pragma unroll
    for (int j = 0; j < 4; ++j)
      acc[i][j] = (floatx4){0.f, 0.f, 0.f, 0.f};

  const bf16_t* Ab = A + (size_t)blockIdx.x * 128 * K;
  const bf16_t* Bb = B + (size_t)blockIdx.y * 128 * K;

  auto stage = [&](int buf, int k0) {
    #pragma unroll
    for (int i = 0; i < 4; ++i) {
      int c = tid + 256 * i;
      int row = c >> 3, colc = c & 7;
      int gofs = ((colc ^ (row & 7)) << 3);
      GLDS16(&Ab[(size_t)row * K + k0 + gofs], &As[buf][c * 8]);
      GLDS16(&Bb[(size_t)row * K + k0 + gofs], &Bs[buf][c * 8]);
    }
  };

  stage(0, 0);
  for (int it = 0; it < 8; ++it) {
    const int cur = it & 1;
    __syncthreads();
    if (it + 1 < 8) stage(cur ^ 1, (it + 1) << 6);
    #pragma unroll
    for (int ks = 0; ks < 2; ++ks) {
      bf16x8 af[4], bfr[4];
      #pragma unroll
      for (int t = 0; t < 4; ++t) {
        af[t]  = *(const bf16x8*)&As[cur][(wm * 64 + t * 16 + l15) * 64 +
                                         (((ks * 4 + quad) ^ l7) << 3)];
        bfr[t] = *(const bf16x8*)&Bs[cur][(wn * 64 + t * 16 + l15) * 64 +
                                         (((ks * 4 + quad) ^ l7) << 3)];
      }
      #pragma unroll
      for (int mt = 0; mt < 4; ++mt)
        #pragma unroll
        for (int nt = 0; nt < 4; ++nt)
          acc[mt][nt] = mfma16(af[mt], bfr[nt], acc[mt][nt]);
    }
  }

  if (blockIdx.y < 8) {
    // ---- Q / K scatter epilogue ----
    #pragma unroll
    for (int mt = 0; mt < 4; ++mt) {
      #pragma unroll
      for (int nt = 0; nt < 4; ++nt) {
        #pragma unroll
        for (int r = 0; r < 4; ++r) {
          int m = blockIdx.x * 128 + wm * 64 + mt * 16 + quad * 4 + r;
          int n = blockIdx.y * 128 + wn * 64 + nt * 16 + l15;
          float v = acc[mt][nt][r];
          int b = m >> 12, t = m & 4095;
          int h = (n >> 6) & 7, d = n & 63;
          size_t bh = (size_t)(b * 8 + h);
          if (n < 512)   // fold 1/sqrt(64) * log2(e) -> softmax in log2 domain
            Qo[bh * 262144 + (size_t)t * 64 + d] = (bf16_t)(v * 0.18033688f);
          else           // K fragment-linear
            Ko[bh * 262144 +
               (size_t)((((t >> 4) * 2 + (d >> 5)) * 512) +
                        ((((d & 31) >> 3) * 16 + (t & 15)) * 8) + (d & 7))] =
                (bf16_t)v;
        }
      }
    }
  } else {
    // ---- V epilogue: transpose through LDS (As region, 32 KB) ----
    __syncthreads();                       // everyone done reading As/Bs
    bf16_t* L = &As[0][0];                 // [n_local][m swizzled] 128x128
    #pragma unroll
    for (int mt = 0; mt < 4; ++mt)
      #pragma unroll
      for (int nt = 0; nt < 4; ++nt) {
        int n_l = wn * 64 + nt * 16 + l15;
        int mc  = wm * 8 + mt * 2 + (quad >> 1);     // m-chunk of 8
        bf16x4 v4;
        #pragma unroll
        for (int r = 0; r < 4; ++r) v4[r] = (bf16_t)acc[mt][nt][r];
        *(bf16x4*)&L[n_l * 128 + ((mc ^ (n_l & 15)) << 3) + (quad & 1) * 4] = v4;
      }
    __syncthreads();
    const int t0 = (blockIdx.x & 31) * 128;
    const int b  = blockIdx.x >> 5;
    #pragma unroll
    for (int i = 0; i < 8; ++i) {
      int c = tid + 256 * i;               // 0..2047: n_l = c>>4, tc = c&15
      int n_l = c >> 4, tc = c & 15;
      int h = ((blockIdx.y - 8) << 1) | (n_l >> 6);
      int d = n_l & 63;
      size_t bh = (size_t)(b * 8 + h);
      int base0 = (tc >> 2) * 32 + (tc & 3) * 4;
      bf16x4 lo = *(const bf16x4*)&L[n_l * 128 +
                     (((base0 >> 3) ^ (n_l & 15)) << 3) + (base0 & 7)];
      bf16x4 hi = *(const bf16x4*)&L[n_l * 128 +
                     ((((base0 + 16) >> 3) ^ (n_l & 15)) << 3) + (base0 & 7)];
      bf16x8 o;
      #pragma unroll
      for (int e = 0; e < 4; ++e) { o[e] = lo[e]; o[e + 4] = hi[e]; }
      int T = t0 + tc * 8;                 // t' base of this 8-chunk
      *(bf16x8*)&Vto[bh * 262144 +
                     (size_t)((((T >> 5) * 4 + (d >> 4)) * 512) +
                              ((((T >> 3) & 3) * 16 + (d & 15)) * 8))] = o;
    }
  }
}

// ---------------- output GEMM: out(8192,512) = Ob(8192,512) * Wo(512,512)^T ----
__global__ __launch_bounds__(256) void gemm_out(
    const bf16_t* __restrict__ A, const bf16_t* __restrict__ B,
    float* __restrict__ Cf)
{
  __shared__ __align__(16) bf16_t As[2][64 * 64];
  __shared__ __align__(16) bf16_t Bs[2][128 * 64];
  const int tid  = threadIdx.x;
  const int lane = tid & 63;
  const int w    = tid >> 6;               // 0..3, owns n-range w*32..+32
  const int quad = lane >> 4;
  const int l15  = lane & 15;
  const int l7   = lane & 7;

  floatx4 acc[4][2];
  #pragma unroll
  for (int i = 0; i < 4; ++i)
    #pragma unroll
    for (int j = 0; j < 2; ++j)
      acc[i][j] = (floatx4){0.f, 0.f, 0.f, 0.f};

  const bf16_t* Ab = A + (size_t)blockIdx.x * 64 * 512;
  const bf16_t* Bb = B + (size_t)blockIdx.y * 128 * 512;

  auto stage = [&](int buf, int k0) {
    #pragma unroll
    for (int i = 0; i < 2; ++i) {          // A: 512 chunks
      int c = tid + 256 * i;
      int row = c >> 3, colc = c & 7;
      GLDS16(&Ab[(size_t)row * 512 + k0 + ((colc ^ (row & 7)) << 3)],
             &As[buf][c * 8]);
    }
    #pragma unroll
    for (int i = 0; i < 4; ++i) {          // B: 1024 chunks
      int c = tid + 256 * i;
      int row = c >> 3, colc = c & 7;
      GLDS16(&Bb[(size_t)row * 512 + k0 + ((colc ^ (row & 7)) << 3)],
             &Bs[buf][c * 8]);
    }
  };

  stage(0, 0);
  for (int it = 0; it < 8; ++it) {
    const int cur = it & 1;
    __syncthreads();
    if (it + 1 < 8) stage(cur ^ 1, (it + 1) << 6);
    #pragma unroll
    for (int ks = 0; ks < 2; ++ks) {
      bf16x8 af[4], bfr[2];
      #pragma unroll
      for (int t = 0; t < 4; ++t)
        af[t]  = *(const bf16x8*)&As[cur][(t * 16 + l15) * 64 +
                                         (((ks * 4 + quad) ^ l7) << 3)];
      #pragma unroll
      for (int t = 0; t < 2; ++t)
        bfr[t] = *(const bf16x8*)&Bs[cur][(w * 32 + t * 16 + l15) * 64 +
                                         (((ks * 4 + quad) ^ l7) << 3)];
      #pragma unroll
      for (int mt = 0; mt < 4; ++mt)
        #pragma unroll
        for (int nt = 0; nt < 2; ++nt)
          acc[mt][nt] = mfma16(af[mt], bfr[nt], acc[mt][nt]);
    }
  }

  #pragma unroll
  for (int mt = 0; mt < 4; ++mt)
    #pragma unroll
    for (int nt = 0; nt < 2; ++nt)
      #pragma unroll
      for (int r = 0; r < 4; ++r) {
        int m = blockIdx.x * 64 + mt * 16 + quad * 4 + r;
        int n = blockIdx.y * 128 + w * 32 + nt * 16 + l15;
        Cf[(size_t)m * 512 + n] = acc[mt][nt][r];
      }
}

// ---- causal flash attention: register-direct, 2 blocks/CU, 4 waves/SIMD ----
// 512 blocks x 512 threads, LDS 67.6 KB -> 2 blocks/CU by LDS alone. NOTE:
// __launch_bounds__(512, 1) — NOT (512,4): R11's (512,4) forced a 64-VGPR
// regalloc budget on the unified VGPR/AGPR file and spilled the whole working
// set to scratch (1.6 GB HBM traffic, 384 us). The hint is unnecessary:
// hardware occupancy = min(LDS-limited 2 blocks/CU, VGPR-limited) and at the
// natural 128-VGPR allocation (R10-verified) the register file supports far
// more than 16 waves/CU. Block owns the 64-row q-block pair (q64A=63-y,
// q64B=y) of one bh, processed SEQUENTIALLY; 8 waves = k64 residues mod 8 ->
// per-wave units 8.1 +- 1, uniform across waves AND blocks. Inner body = R10
// (64q x 64k: 72 MFMA / 16 coalesced dwordx4 fragment loads / 64 exp2; zero
// main-loop barriers -> 4 independent streams per SIMD overlap MFMA, exp2,
// and L2 latency). Epilogue per tile: two d-half rounds over
// PART[kq][64q][32d] f32 (64 KB, XOR chunk swizzle) + all-thread 8-way merge.
// No-max log2-domain softmax (scores bounded, fp32-safe).
__global__ __launch_bounds__(512, 1) void attn_kernel(
    const bf16_t* __restrict__ Qg, const bf16_t* __restrict__ Kf,
    const bf16_t* __restrict__ Vf, bf16_t* __restrict__ Og)
{
  // PART[kq 0..7][64q][32d] f32 = 65536 B ; PL[kq][64q] f32 = 2048 B
  __shared__ __align__(16) bf16_t smem[33792];   // 67,584 B

  const int tid  = threadIdx.x;
  const int lane = tid & 63;
  const int kq   = tid >> 6;               // wave = k64 residue class 0..7
  const int quad = lane >> 4;
  const int l15  = lane & 15;

  const int id = blockIdx.x;               // 0..511
  const int bh = 2 * (id & 7) + ((id >> 3) & 1);   // 2 bh per XCD (L2 reuse)
  const int y  = id >> 4;                  // 0..31
  const int q64A = 63 - y, q64B = y;
  const size_t bh_off = (size_t)bh * 262144;
  const int b = bh >> 3, h = bh & 7;

  const bf16_t* Kb_ = Kf + bh_off;
  const bf16_t* Vb_ = Vf + bh_off;
  const floatx4 z4 = (floatx4){0.f, 0.f, 0.f, 0.f};
  bf16x8 ones;
  #pragma unroll
  for (int i = 0; i < 8; ++i) ones[i] = (bf16_t)1.0f;

  for (int ph = 0; ph < 2; ++ph) {
    const int q64 = ph ? q64B : q64A;      // wave's 64-row q-block index
    const int qbase = q64 * 64;

    // Q fragments (pre-scaled by 0.125*log2e): 4 q-blocks of 16 rows
    bf16x8 aq0[4], aq1[4];
    #pragma unroll
    for (int qb = 0; qb < 4; ++qb) {
      const bf16_t* Qp = Qg + bh_off + (size_t)(qbase + qb * 16 + l15) * 64;
      aq0[qb] = *(const bf16x8*)&Qp[quad * 8];
      aq1[qb] = *(const bf16x8*)&Qp[32 + quad * 8];
    }

    floatx4 acc_o[4][4], acc_l[4];
    #pragma unroll
    for (int qb = 0; qb < 4; ++qb) {
      #pragma unroll
      for (int dt = 0; dt < 4; ++dt) acc_o[qb][dt] = (floatx4){0.f, 0.f, 0.f, 0.f};
      acc_l[qb] = (floatx4){0.f, 0.f, 0.f, 0.f};
    }

    for (int k64 = kq; k64 <= q64; k64 += 8) {
      const bf16_t* Kp = Kb_ + (size_t)k64 * 4096;   // 8 K-frags of 512 elems
      const bf16_t* Vp = Vb_ + (size_t)k64 * 4096;   // 8 V-frags of 512 elems
      // ---- K fragment loads: coalesced, L2-hot ----
      bf16x8 bk0[4], bk1[4];
      #pragma unroll
      for (int nt = 0; nt < 4; ++nt) {
        bk0[nt] = *(const bf16x8*)&Kp[(nt * 2 + 0) * 512 + lane * 8];
        bk1[nt] = *(const bf16x8*)&Kp[(nt * 2 + 1) * 512 + lane * 8];
      }
      // ---- S^T = K Q^T : 64 k-rows x 64 q-cols ----
      floatx4 s[4][4];                     // [qb][nt]
      #pragma unroll
      for (int nt = 0; nt < 4; ++nt) {
        s[0][nt] = mfma16(bk0[nt], aq0[0], z4);
        s[1][nt] = mfma16(bk0[nt], aq0[1], z4);
        s[2][nt] = mfma16(bk0[nt], aq0[2], z4);
        s[3][nt] = mfma16(bk0[nt], aq0[3], z4);
      }
      #pragma unroll
      for (int nt = 0; nt < 4; ++nt)
        #pragma unroll
        for (int qb = 0; qb < 4; ++qb)
          s[qb][nt] = mfma16(bk1[nt], aq1[qb], s[qb][nt]);
      // ---- V fragment loads (latency hides under exp2) ----
      bf16x8 av[2][4];
      #pragma unroll
      for (int kc = 0; kc < 2; ++kc)
        #pragma unroll
        for (int dt = 0; dt < 4; ++dt)
          av[kc][dt] = *(const bf16x8*)&Vp[(kc * 4 + dt) * 512 + lane * 8];
      // ---- no-max softmax, log2 domain ----
      if (k64 == q64) {                    // diagonal 64-block: mask k > q
        #pragma unroll
        for (int qb = 0; qb < 4; ++qb)
          #pragma unroll
          for (int nt = 0; nt < 4; ++nt)
            #pragma unroll
            for (int r = 0; r < 4; ++r)
              if (nt * 16 + quad * 4 + r > qb * 16 + l15)
                s[qb][nt][r] = -3.0e38f;
      }
      #pragma unroll
      for (int qb = 0; qb < 4; ++qb)
        #pragma unroll
        for (int nt = 0; nt < 4; ++nt)
          #pragma unroll
          for (int r = 0; r < 4; ++r)
            s[qb][nt][r] = __builtin_amdgcn_exp2f(s[qb][nt][r]);
      // ---- PV: O^T += V^T P^T ; l += 1^T P^T ----
      #pragma unroll
      for (int kc = 0; kc < 2; ++kc) {
        bf16x8 pb[4];
        #pragma unroll
        for (int qb = 0; qb < 4; ++qb)
          #pragma unroll
          for (int r = 0; r < 4; ++r) {
            pb[qb][r]     = (bf16_t)s[qb][kc * 2][r];
            pb[qb][r + 4] = (bf16_t)s[qb][kc * 2 + 1][r];
          }
        #pragma unroll
        for (int qb = 0; qb < 4; ++qb)
          acc_l[qb] = mfma16(ones, pb[qb], acc_l[qb]);
        #pragma unroll
        for (int dt = 0; dt < 4; ++dt)
          #pragma unroll
          for (int qb = 0; qb < 4; ++qb)
            acc_o[qb][dt] = mfma16(av[kc][dt], pb[qb], acc_o[qb][dt]);
      }
    }

    // ---- epilogue: two d-half rounds, 8-way k-partial merge in LDS ----
    #pragma unroll
    for (int hd = 0; hd < 2; ++hd) {
      if (ph | hd) __syncthreads();        // prior merge reads done
      {                                    // write this wave's partial half
        float* Pw  = (float*)&smem[0] + kq * 2048;      // [64q][32d]
        float* PLw = (float*)&smem[32768];              // [kq][64q]
        #pragma unroll
        for (int qb = 0; qb < 4; ++qb) {
          int q = qb * 16 + l15;
          #pragma unroll
          for (int t = 0; t < 2; ++t) {    // logical chunk = t*4+quad (4d each)
            int cw = (t * 4 + quad) ^ (q & 7);          // bank-even XOR swizzle
            *(floatx4*)&Pw[q * 32 + cw * 4] = acc_o[qb][hd * 2 + t];
          }
          if (hd == 0 && quad == 0) PLw[kq * 64 + q] = acc_l[qb][0];
        }
      }
      __syncthreads();
      {                                    // all-thread merge + store
        int q = tid >> 3, c = tid & 7;     // 64 q x 8 chunks of 4d
        const float* PB = (const float*)&smem[0];
        const float* PL = (const float*)&smem[32768];
        floatx4 ssum = (floatx4){0.f, 0.f, 0.f, 0.f};
        float suml = 0.f;
        #pragma unroll
        for (int k = 0; k < 8; ++k) {
          const float* Pk = PB + k * 2048 + q * 32;
          floatx4 u = *(const floatx4*)&Pk[(c ^ (q & 7)) * 4];
          #pragma unroll
          for (int r = 0; r < 4; ++r) ssum[r] += u[r];
          suml += PL[k * 64 + q];
        }
        float rl = 1.0f / suml;
        bf16x4 o4;
        #pragma unroll
        for (int r = 0; r < 4; ++r) o4[r] = (bf16_t)(ssum[r] * rl);
        int row = qbase + q;
        *(bf16x4*)&Og[((size_t)b * 4096 + row) * 512 + h * 64 + hd * 32 + c * 4] = o4;
      }
    }
  }
}

// ---------------- launcher ----------------
extern "C" void kernel_launch(void* const* d_in, const int* in_sizes, int n_in,
                              void* d_out, int out_size, void* d_ws, size_t ws_size,
                              hipStream_t stream) {
  const float* x    = (const float*)d_in[0];   // (2,4096,512)
  const float* wqkv = (const float*)d_in[1];   // (1536,512)
  const float* wo   = (const float*)d_in[2];   // (512,512)
  float* out = (float*)d_out;                  // (2,4096,512) fp32

  char* ws = (char*)d_ws;
  bf16_t* xb    = (bf16_t*)(ws);                 //  8 MB (reused as Ob after gemm1)
  bf16_t* wqkvb = (bf16_t*)(ws + 8388608);       //  1.5 MB
  bf16_t* wob   = (bf16_t*)(ws + 9961472);       //  0.5 MB
  bf16_t* Qb    = (bf16_t*)(ws + 10485760);      //  8 MB  [bh][t][64], pre-scaled
  bf16_t* Kfb   = (bf16_t*)(ws + 18874368);      //  8 MB  K fragment-linear
  bf16_t* Vfb   = (bf16_t*)(ws + 27262976);      //  8 MB  V^T fragment-linear
  bf16_t* Ob    = xb;                            //  alias: gemm1 done with xb
  // total 35,651,584 bytes

  cvt_all_kernel<<<5120, 256, 0, stream>>>(x, wqkv, wo, xb, wqkvb, wob);

  gemm_qkv<<<dim3(64, 12), 256, 0, stream>>>(xb, wqkvb, Qb, Kfb, Vfb);
  attn_kernel<<<dim3(512), 512, 0, stream>>>(Qb, Kfb, Vfb, Ob);
  gemm_out<<<dim3(128, 4), 256, 0, stream>>>(Ob, wob, out);
}

// Round 13
// 152.726 us; speedup vs baseline: 2.9939x; 1.0004x over previous
//
#include <hip/hip_runtime.h>
#include <hip/hip_bf16.h>

typedef __bf16 bf16_t;
typedef __bf16 bf16x8 __attribute__((ext_vector_type(8)));
typedef __bf16 bf16x4 __attribute__((ext_vector_type(4)));
typedef float  floatx4 __attribute__((ext_vector_type(4)));

static __device__ __forceinline__ floatx4 mfma16(bf16x8 a, bf16x8 b, floatx4 c) {
  return __builtin_amdgcn_mfma_f32_16x16x32_bf16(a, b, c, 0, 0, 0);
}

// async global->LDS, 16B per lane; LDS dest = wave-uniform base + lane*16.
typedef __attribute__((address_space(3))) void lds_vp;
typedef __attribute__((address_space(1))) void glb_vp;
#define GLDS16(g, l) \
  __builtin_amdgcn_global_load_lds((glb_vp*)(g), (lds_vp*)(l), 16, 0, 0)

// ---------------- weights fp32 -> bf16 (wqkv, wo only; x is fused into gemm) ----
__global__ void cvt_w_kernel(const float* __restrict__ wqkv,
                             const float* __restrict__ wo,
                             bf16_t* __restrict__ wqkvb,
                             bf16_t* __restrict__ wob) {
  int i = blockIdx.x * blockDim.x + threadIdx.x;     // 0..262143 float4s
  const float4* src; bf16x4* dst; int off;
  if (i < 196608) { src = (const float4*)wqkv; dst = (bf16x4*)wqkvb; off = i; }
  else            { src = (const float4*)wo;   dst = (bf16x4*)wob;   off = i - 196608; }
  float4 v = src[off];
  bf16x4 o;
  o[0] = (bf16_t)v.x; o[1] = (bf16_t)v.y; o[2] = (bf16_t)v.z; o[3] = (bf16_t)v.w;
  dst[off] = o;
}

// ---------------- QKV GEMM: C(M,N) = A(M,K) * B(N,K)^T ----------------
// A = x read DIRECTLY as fp32 (conversion fused into staging, T14 split:
// issue float4 loads early -> compute -> cvt+ds_write late). B = wqkvb bf16
// via GLDS16 (unchanged). Epilogues write attn-ready layouts:
//   Q  [bh][t][64] pre-scaled by 0.125*log2e (softmax in log2 domain)
//   Kf [bh][t>>4][d>>5][lane][8]  MFMA-A-fragment-linear: lane=((d&31)>>3)*16+(t&15)
//   Vf [bh][t'>>5][d>>4][lane][8] V^T fragment-linear:    lane=((t'>>3)&3)*16+(d&15)
__global__ __launch_bounds__(256) void gemm_qkv(
    const float* __restrict__ A, const bf16_t* __restrict__ B,
    bf16_t* __restrict__ Qo, bf16_t* __restrict__ Ko, bf16_t* __restrict__ Vto)
{
  __shared__ __align__(16) bf16_t As[2][128 * 64];
  __shared__ __align__(16) bf16_t Bs[2][128 * 64];
  const int tid  = threadIdx.x;
  const int lane = tid & 63;
  const int w    = tid >> 6;
  const int quad = lane >> 4;
  const int l15  = lane & 15;
  const int l7   = lane & 7;
  const int wm   = w & 1;
  const int wn   = w >> 1;
  const int K    = 512;

  floatx4 acc[4][4];
  #pragma unroll
  for (int i = 0; i < 4; ++i)
    #pragma unroll
    for (int j = 0; j < 4; ++j)
      acc[i][j] = (floatx4){0.f, 0.f, 0.f, 0.f};

  const float*  Ab = A + (size_t)blockIdx.x * 128 * K;
  const bf16_t* Bb = B + (size_t)blockIdx.y * 128 * K;

  float4 ar[4][2];                         // in-flight A fp32 tile (32 VGPR)
  auto loadA = [&](int k0) {               // issue 8 float4 loads (async)
    #pragma unroll
    for (int i = 0; i < 4; ++i) {
      int c = tid + 256 * i;
      int row = c >> 3, colc = c & 7;
      const float* pa = &Ab[(size_t)row * K + k0 + ((colc ^ (row & 7)) << 3)];
      ar[i][0] = *(const float4*)pa;
      ar[i][1] = *(const float4*)(pa + 4);
    }
  };
  auto writeA = [&](int buf) {             // cvt + ds_write (after compute)
    #pragma unroll
    for (int i = 0; i < 4; ++i) {
      int c = tid + 256 * i;
      bf16x8 av;
      av[0] = (bf16_t)ar[i][0].x; av[1] = (bf16_t)ar[i][0].y;
      av[2] = (bf16_t)ar[i][0].z; av[3] = (bf16_t)ar[i][0].w;
      av[4] = (bf16_t)ar[i][1].x; av[5] = (bf16_t)ar[i][1].y;
      av[6] = (bf16_t)ar[i][1].z; av[7] = (bf16_t)ar[i][1].w;
      *(bf16x8*)&As[buf][c * 8] = av;
    }
  };
  auto stageB = [&](int buf, int k0) {
    #pragma unroll
    for (int i = 0; i < 4; ++i) {
      int c = tid + 256 * i;
      int row = c >> 3, colc = c & 7;
      GLDS16(&Bb[(size_t)row * K + k0 + ((colc ^ (row & 7)) << 3)], &Bs[buf][c * 8]);
    }
  };

  loadA(0);
  writeA(0);                               // one-time prologue stall on A(0)
  stageB(0, 0);
  for (int it = 0; it < 8; ++it) {
    const int cur = it & 1;
    __syncthreads();                       // drains B(it) GLDS + A writes
    if (it + 1 < 8) {
      stageB(cur ^ 1, (it + 1) << 6);      // async, lands during compute
      loadA((it + 1) << 6);                // async, consumed after compute
    }
    #pragma unroll
    for (int ks = 0; ks < 2; ++ks) {
      bf16x8 af[4], bfr[4];
      #pragma unroll
      for (int t = 0; t < 4; ++t) {
        af[t]  = *(const bf16x8*)&As[cur][(wm * 64 + t * 16 + l15) * 64 +
                                         (((ks * 4 + quad) ^ l7) << 3)];
        bfr[t] = *(const bf16x8*)&Bs[cur][(wn * 64 + t * 16 + l15) * 64 +
                                         (((ks * 4 + quad) ^ l7) << 3)];
      }
      #pragma unroll
      for (int mt = 0; mt < 4; ++mt)
        #pragma unroll
        for (int nt = 0; nt < 4; ++nt)
          acc[mt][nt] = mfma16(af[mt], bfr[nt], acc[mt][nt]);
    }
    if (it + 1 < 8) writeA(cur ^ 1);       // cvt+write after compute (T14)
  }

  if (blockIdx.y < 8) {
    // ---- Q / K scatter epilogue ----
    #pragma unroll
    for (int mt = 0; mt < 4; ++mt) {
      #pragma unroll
      for (int nt = 0; nt < 4; ++nt) {
        #pragma unroll
        for (int r = 0; r < 4; ++r) {
          int m = blockIdx.x * 128 + wm * 64 + mt * 16 + quad * 4 + r;
          int n = blockIdx.y * 128 + wn * 64 + nt * 16 + l15;
          float v = acc[mt][nt][r];
          int b = m >> 12, t = m & 4095;
          int h = (n >> 6) & 7, d = n & 63;
          size_t bh = (size_t)(b * 8 + h);
          if (n < 512)   // fold 1/sqrt(64) * log2(e) -> softmax in log2 domain
            Qo[bh * 262144 + (size_t)t * 64 + d] = (bf16_t)(v * 0.18033688f);
          else           // K fragment-linear
            Ko[bh * 262144 +
               (size_t)((((t >> 4) * 2 + (d >> 5)) * 512) +
                        ((((d & 31) >> 3) * 16 + (t & 15)) * 8) + (d & 7))] =
                (bf16_t)v;
        }
      }
    }
  } else {
    // ---- V epilogue: transpose through LDS (As region, 32 KB) ----
    __syncthreads();                       // everyone done reading As/Bs
    bf16_t* L = &As[0][0];                 // [n_local][m swizzled] 128x128
    #pragma unroll
    for (int mt = 0; mt < 4; ++mt)
      #pragma unroll
      for (int nt = 0; nt < 4; ++nt) {
        int n_l = wn * 64 + nt * 16 + l15;
        int mc  = wm * 8 + mt * 2 + (quad >> 1);     // m-chunk of 8
        bf16x4 v4;
        #pragma unroll
        for (int r = 0; r < 4; ++r) v4[r] = (bf16_t)acc[mt][nt][r];
        *(bf16x4*)&L[n_l * 128 + ((mc ^ (n_l & 15)) << 3) + (quad & 1) * 4] = v4;
      }
    __syncthreads();
    const int t0 = (blockIdx.x & 31) * 128;
    const int b  = blockIdx.x >> 5;
    #pragma unroll
    for (int i = 0; i < 8; ++i) {
      int c = tid + 256 * i;               // 0..2047: n_l = c>>4, tc = c&15
      int n_l = c >> 4, tc = c & 15;
      int h = ((blockIdx.y - 8) << 1) | (n_l >> 6);
      int d = n_l & 63;
      size_t bh = (size_t)(b * 8 + h);
      int base0 = (tc >> 2) * 32 + (tc & 3) * 4;
      bf16x4 lo = *(const bf16x4*)&L[n_l * 128 +
                     (((base0 >> 3) ^ (n_l & 15)) << 3) + (base0 & 7)];
      bf16x4 hi = *(const bf16x4*)&L[n_l * 128 +
                     ((((base0 + 16) >> 3) ^ (n_l & 15)) << 3) + (base0 & 7)];
      bf16x8 o;
      #pragma unroll
      for (int e = 0; e < 4; ++e) { o[e] = lo[e]; o[e + 4] = hi[e]; }
      int T = t0 + tc * 8;                 // t' base of this 8-chunk
      *(bf16x8*)&Vto[bh * 262144 +
                     (size_t)((((T >> 5) * 4 + (d >> 4)) * 512) +
                              ((((T >> 3) & 3) * 16 + (d & 15)) * 8))] = o;
    }
  }
}

// ---------------- output GEMM: out(8192,512) = Ob(8192,512) * Wo(512,512)^T ----
__global__ __launch_bounds__(256) void gemm_out(
    const bf16_t* __restrict__ A, const bf16_t* __restrict__ B,
    float* __restrict__ Cf)
{
  __shared__ __align__(16) bf16_t As[2][64 * 64];
  __shared__ __align__(16) bf16_t Bs[2][128 * 64];
  const int tid  = threadIdx.x;
  const int lane = tid & 63;
  const int w    = tid >> 6;               // 0..3, owns n-range w*32..+32
  const int quad = lane >> 4;
  const int l15  = lane & 15;
  const int l7   = lane & 7;

  floatx4 acc[4][2];
  #pragma unroll
  for (int i = 0; i < 4; ++i)
    #pragma unroll
    for (int j = 0; j < 2; ++j)
      acc[i][j] = (floatx4){0.f, 0.f, 0.f, 0.f};

  const bf16_t* Ab = A + (size_t)blockIdx.x * 64 * 512;
  const bf16_t* Bb = B + (size_t)blockIdx.y * 128 * 512;

  auto stage = [&](int buf, int k0) {
    #pragma unroll
    for (int i = 0; i < 2; ++i) {          // A: 512 chunks
      int c = tid + 256 * i;
      int row = c >> 3, colc = c & 7;
      GLDS16(&Ab[(size_t)row * 512 + k0 + ((colc ^ (row & 7)) << 3)],
             &As[buf][c * 8]);
    }
    #pragma unroll
    for (int i = 0; i < 4; ++i) {          // B: 1024 chunks
      int c = tid + 256 * i;
      int row = c >> 3, colc = c & 7;
      GLDS16(&Bb[(size_t)row * 512 + k0 + ((colc ^ (row & 7)) << 3)],
             &Bs[buf][c * 8]);
    }
  };

  stage(0, 0);
  for (int it = 0; it < 8; ++it) {
    const int cur = it & 1;
    __syncthreads();
    if (it + 1 < 8) stage(cur ^ 1, (it + 1) << 6);
    #pragma unroll
    for (int ks = 0; ks < 2; ++ks) {
      bf16x8 af[4], bfr[2];
      #pragma unroll
      for (int t = 0; t < 4; ++t)
        af[t]  = *(const bf16x8*)&As[cur][(t * 16 + l15) * 64 +
                                         (((ks * 4 + quad) ^ l7) << 3)];
      #pragma unroll
      for (int t = 0; t < 2; ++t)
        bfr[t] = *(const bf16x8*)&Bs[cur][(w * 32 + t * 16 + l15) * 64 +
                                         (((ks * 4 + quad) ^ l7) << 3)];
      #pragma unroll
      for (int mt = 0; mt < 4; ++mt)
        #pragma unroll
        for (int nt = 0; nt < 2; ++nt)
          acc[mt][nt] = mfma16(af[mt], bfr[nt], acc[mt][nt]);
    }
  }

  #pragma unroll
  for (int mt = 0; mt < 4; ++mt)
    #pragma unroll
    for (int nt = 0; nt < 2; ++nt)
      #pragma unroll
      for (int r = 0; r < 4; ++r) {
        int m = blockIdx.x * 64 + mt * 16 + quad * 4 + r;
        int n = blockIdx.y * 128 + w * 32 + nt * 16 + l15;
        Cf[(size_t)m * 512 + n] = acc[mt][nt][r];
      }
}

// ---- causal flash attention: register-direct, balanced barrier-free waves ----
// (R10 verbatim — best measured: 45.7 us, MfmaUtil 33%.) 256 blocks x 512
// threads (8 waves), 1 block/CU. Waves = {qh} x {kq in 0..3}; each wave steps
// k64 by 4 and processes tile qtA then qtB SEQUENTIALLY -> per-wave iterations
// ~ 15.75 +- 1, uniform across waves AND blocks. K/V read DIRECTLY from global
// in fragment-linear layout (coalesced dwordx4, L2-resident). Zero main-loop
// barriers. Epilogue per tile: 4 kq-partials to LDS (133 KB, epilogue-only),
// all-thread merge + normalize + direct Og store. No-max log2-domain softmax.
__global__ __launch_bounds__(512, 1) void attn_kernel(
    const bf16_t* __restrict__ Qg, const bf16_t* __restrict__ Kf,
    const bf16_t* __restrict__ Vf, bf16_t* __restrict__ Og)
{
  // PART[qh][kq][64q][64d] f32 = 131072 B ; PL[qh][kq][64] f32 = 2048 B
  __shared__ __align__(16) bf16_t smem[66560];   // 133,120 B

  const int tid  = threadIdx.x;
  const int lane = tid & 63;
  const int w    = tid >> 6;               // 0..7
  const int qh   = w >> 2;                 // q 64-half of the 128-row tile
  const int kq   = w & 3;                  // k64 residue class this wave owns
  const int quad = lane >> 4;
  const int l15  = lane & 15;

  const int id = blockIdx.x;               // 0..255
  const int bh = 2 * (id & 7) + ((id >> 3) & 1);   // 2 bh per XCD (L2 reuse)
  const int x  = id >> 4;                  // 0..15
  const int qtA = 31 - x, qtB = x;
  const size_t bh_off = (size_t)bh * 262144;
  const int b = bh >> 3, h = bh & 7;

  const bf16_t* Kb_ = Kf + bh_off;
  const bf16_t* Vb_ = Vf + bh_off;
  const floatx4 z4 = (floatx4){0.f, 0.f, 0.f, 0.f};
  bf16x8 ones;
  #pragma unroll
  for (int i = 0; i < 8; ++i) ones[i] = (bf16_t)1.0f;

  for (int ph = 0; ph < 2; ++ph) {
    const int qt   = ph ? qtB : qtA;
    const int q64  = 2 * qt + qh;          // wave's 64-row q-block index
    const int qbase = qt * 128 + qh * 64;

    // Q fragments (pre-scaled by 0.125*log2e): 4 q-blocks of 16 rows
    bf16x8 aq0[4], aq1[4];
    #pragma unroll
    for (int qb = 0; qb < 4; ++qb) {
      const bf16_t* Qp = Qg + bh_off + (size_t)(qbase + qb * 16 + l15) * 64;
      aq0[qb] = *(const bf16x8*)&Qp[quad * 8];
      aq1[qb] = *(const bf16x8*)&Qp[32 + quad * 8];
    }

    floatx4 acc_o[4][4], acc_l[4];
    #pragma unroll
    for (int qb = 0; qb < 4; ++qb) {
      #pragma unroll
      for (int dt = 0; dt < 4; ++dt) acc_o[qb][dt] = (floatx4){0.f, 0.f, 0.f, 0.f};
      acc_l[qb] = (floatx4){0.f, 0.f, 0.f, 0.f};
    }

    for (int k64 = kq; k64 <= q64; k64 += 4) {
      const bf16_t* Kp = Kb_ + (size_t)k64 * 4096;   // 8 K-frags of 512 elems
      const bf16_t* Vp = Vb_ + (size_t)k64 * 4096;   // 8 V-frags of 512 elems
      // ---- K fragment loads: coalesced, L2-hot ----
      bf16x8 bk0[4], bk1[4];
      #pragma unroll
      for (int nt = 0; nt < 4; ++nt) {
        bk0[nt] = *(const bf16x8*)&Kp[(nt * 2 + 0) * 512 + lane * 8];
        bk1[nt] = *(const bf16x8*)&Kp[(nt * 2 + 1) * 512 + lane * 8];
      }
      // ---- S^T = K Q^T : 64 k-rows x 64 q-cols ----
      floatx4 s[4][4];                     // [qb][nt]
      #pragma unroll
      for (int nt = 0; nt < 4; ++nt) {
        s[0][nt] = mfma16(bk0[nt], aq0[0], z4);
        s[1][nt] = mfma16(bk0[nt], aq0[1], z4);
        s[2][nt] = mfma16(bk0[nt], aq0[2], z4);
        s[3][nt] = mfma16(bk0[nt], aq0[3], z4);
      }
      #pragma unroll
      for (int nt = 0; nt < 4; ++nt)
        #pragma unroll
        for (int qb = 0; qb < 4; ++qb)
          s[qb][nt] = mfma16(bk1[nt], aq1[qb], s[qb][nt]);
      // ---- V fragment loads (latency hides under exp2) ----
      bf16x8 av[2][4];
      #pragma unroll
      for (int kc = 0; kc < 2; ++kc)
        #pragma unroll
        for (int dt = 0; dt < 4; ++dt)
          av[kc][dt] = *(const bf16x8*)&Vp[(kc * 4 + dt) * 512 + lane * 8];
      // ---- no-max softmax, log2 domain ----
      if (k64 == q64) {                    // diagonal 64-block: mask k > q
        #pragma unroll
        for (int qb = 0; qb < 4; ++qb)
          #pragma unroll
          for (int nt = 0; nt < 4; ++nt)
            #pragma unroll
            for (int r = 0; r < 4; ++r)
              if (nt * 16 + quad * 4 + r > qb * 16 + l15)
                s[qb][nt][r] = -3.0e38f;
      }
      #pragma unroll
      for (int qb = 0; qb < 4; ++qb)
        #pragma unroll
        for (int nt = 0; nt < 4; ++nt)
          #pragma unroll
          for (int r = 0; r < 4; ++r)
            s[qb][nt][r] = __builtin_amdgcn_exp2f(s[qb][nt][r]);
      // ---- PV: O^T += V^T P^T ; l += 1^T P^T ----
      #pragma unroll
      for (int kc = 0; kc < 2; ++kc) {
        bf16x8 pb[4];
        #pragma unroll
        for (int qb = 0; qb < 4; ++qb)
          #pragma unroll
          for (int r = 0; r < 4; ++r) {
            pb[qb][r]     = (bf16_t)s[qb][kc * 2][r];
            pb[qb][r + 4] = (bf16_t)s[qb][kc * 2 + 1][r];
          }
        #pragma unroll
        for (int qb = 0; qb < 4; ++qb)
          acc_l[qb] = mfma16(ones, pb[qb], acc_l[qb]);
        #pragma unroll
        for (int dt = 0; dt < 4; ++dt)
          #pragma unroll
          for (int qb = 0; qb < 4; ++qb)
            acc_o[qb][dt] = mfma16(av[kc][dt], pb[qb], acc_o[qb][dt]);
      }
    }

    // ---- epilogue: 4 kq-partials -> LDS, all-thread merge + store ----
    {
      float* Pq = (float*)&smem[0] + (qh * 4 + kq) * 4096;   // [64q][64d]
      float* PL = (float*)&smem[65536];                      // [qh][kq][64]
      #pragma unroll
      for (int qb = 0; qb < 4; ++qb) {
        int q = qb * 16 + l15;
        #pragma unroll
        for (int dt = 0; dt < 4; ++dt)
          *(floatx4*)&Pq[q * 64 + (((dt * 4 + quad) ^ l15) << 2)] = acc_o[qb][dt];
        if (quad == 0) PL[(qh * 4 + kq) * 64 + q] = acc_l[qb][0];
      }
    }
    __syncthreads();
    #pragma unroll
    for (int i = 0; i < 2; ++i) {          // 1024 cells: (qh, q, 8d-chunk)
      int a = tid + 512 * i;
      int qh_e = a >> 9, rem = a & 511;
      int q = rem >> 3, c8 = rem & 7;
      const float* Pq = (const float*)&smem[0] + qh_e * 16384;
      const float* PL = (const float*)&smem[65536] + qh_e * 256;
      float s0[8] = {0.f, 0.f, 0.f, 0.f, 0.f, 0.f, 0.f, 0.f};
      float suml = 0.f;
      #pragma unroll
      for (int k2 = 0; k2 < 4; ++k2) {
        const float* Pk = Pq + k2 * 4096 + q * 64;
        floatx4 u0 = *(const floatx4*)&Pk[((c8 * 2)     ^ (q & 15)) << 2];
        floatx4 u1 = *(const floatx4*)&Pk[((c8 * 2 + 1) ^ (q & 15)) << 2];
        #pragma unroll
        for (int r = 0; r < 4; ++r) { s0[r] += u0[r]; s0[4 + r] += u1[r]; }
        suml += PL[k2 * 64 + q];
      }
      float rl = 1.0f / suml;
      bf16x8 o;
      #pragma unroll
      for (int e = 0; e < 8; ++e) o[e] = (bf16_t)(s0[e] * rl);
      int row = qt * 128 + qh_e * 64 + q;
      *(bf16x8*)&Og[((size_t)b * 4096 + row) * 512 + h * 64 + c8 * 8] = o;
    }
    if (ph == 0) __syncthreads();          // PART reads done before B partials
  }
}

// ---------------- launcher ----------------
extern "C" void kernel_launch(void* const* d_in, const int* in_sizes, int n_in,
                              void* d_out, int out_size, void* d_ws, size_t ws_size,
                              hipStream_t stream) {
  const float* x    = (const float*)d_in[0];   // (2,4096,512)
  const float* wqkv = (const float*)d_in[1];   // (1536,512)
  const float* wo   = (const float*)d_in[2];   // (512,512)
  float* out = (float*)d_out;                  // (2,4096,512) fp32

  char* ws = (char*)d_ws;
  bf16_t* Ob    = (bf16_t*)(ws);                 //  8 MB  attn output
  bf16_t* wqkvb = (bf16_t*)(ws + 8388608);       //  1.5 MB
  bf16_t* wob   = (bf16_t*)(ws + 9961472);       //  0.5 MB
  bf16_t* Qb    = (bf16_t*)(ws + 10485760);      //  8 MB  [bh][t][64], pre-scaled
  bf16_t* Kfb   = (bf16_t*)(ws + 18874368);      //  8 MB  K fragment-linear
  bf16_t* Vfb   = (bf16_t*)(ws + 27262976);      //  8 MB  V^T fragment-linear
  // total 35,651,584 bytes

  cvt_w_kernel<<<1024, 256, 0, stream>>>(wqkv, wo, wqkvb, wob);

  gemm_qkv<<<dim3(64, 12), 256, 0, stream>>>(x, wqkvb, Qb, Kfb, Vfb);
  attn_kernel<<<dim3(256), 512, 0, stream>>>(Qb, Kfb, Vfb, Ob);
  gemm_out<<<dim3(128, 4), 256, 0, stream>>>(Ob, wob, out);
}